// Round 2
// baseline (1836.791 us; speedup 1.0000x reference)
//
#include <hip/hip_runtime.h>
#include <hip/hip_cooperative_groups.h>
#include <cstddef>

// Problem constants (B, C, D, H, W) = (2, 2, 128, 256, 256)
#define BZ   2
#define DV   128
#define HV   256
#define WV   256
#define NP   32      // N_PAIRS
#define NIT  10      // N_ITERS
#define RAD  10      // support radius after NIT pool steps
#define BOX  21
#define BOX3 9261
#define ZRAD 11      // zero-init radius (reads extend to RAD+1)
#define ZBOX 23
#define ZBOX3 12167
#define HWV  65536
#define DHW  ((size_t)DV*HWV)
#define SMOOTH 1e-5
#define NBLK 512
#define NTHR 256

namespace cg = cooperative_groups;

// Single persistent cooperative kernel:
//  phase Z : zero radius-11 boxes in both ping-pong buffers + precompute
//            prob = sigmoid(l1-l0) for those voxels (reused by all 10 iters)
//  seed    : heat=1 at the 32 seeds/batch
//  k=0..9  : unnormalized step u_out = avgpool3(u_in)*prob on radius-10
//            boxes; per-block per-batch max -> gpart (plain stores, no hot
//            atomics). Normalization deferred to a scalar recurrence.
//  gather  : reduce gpart -> gmax[k][b], replay s_k = s/(s*g+eps) (guarded),
//            score = s * u_final[eb], out = 1 - mean(score).
__global__ void __launch_bounds__(NTHR, 2)
cape_all(const float* __restrict__ logits,
         const int* __restrict__ ea,
         const int* __restrict__ eb,
         float* __restrict__ out,
         float* __restrict__ buf0,
         float* __restrict__ buf1,
         float* __restrict__ prob,
         float* __restrict__ gpart) {
    cg::grid_group grid = cg::this_grid();
    const int tid = blockIdx.x * blockDim.x + threadIdx.x;
    const int nthreads = gridDim.x * blockDim.x;
    __shared__ float sred[2][4];

    // ---- Phase Z: zero ping-pong boxes + precompute prob ------------------
    for (int i = tid; i < 64 * ZBOX3; i += nthreads) {
        int box = i / ZBOX3, r = i - box * ZBOX3;
        int dz = r / (ZBOX * ZBOX); r -= dz * (ZBOX * ZBOX);
        int dy = r / ZBOX, dx = r - dy * ZBOX;
        int b = box >> 5;
        const int* e = ea + box * 3;
        int d = e[0] + dz - ZRAD, h = e[1] + dy - ZRAD, w = e[2] + dx - ZRAD;
        if (d < 0 || d >= DV || h < 0 || h >= HV || w < 0 || w >= WV) continue;
        size_t off = (size_t)d * HWV + (size_t)h * WV + w;
        size_t idx = (size_t)b * DHW + off;
        buf0[idx] = 0.f;
        buf1[idx] = 0.f;
        const float* lg = logits + (size_t)b * 2 * DHW;
        float l0 = lg[off], l1 = lg[off + DHW];
        prob[idx] = 1.f / (1.f + expf(l0 - l1));   // softmax(C=2)[channel 1]
    }
    __threadfence();
    grid.sync();

    // ---- Seed (after zero: duplicates just rewrite 1.0, matching .set) ----
    if (tid < BZ * NP) {
        const int* e = ea + tid * 3;
        int b = tid / NP;
        buf0[(size_t)b * DHW + (size_t)e[0] * HWV + (size_t)e[1] * WV + e[2]] = 1.0f;
    }
    __threadfence();
    grid.sync();

    // ---- 10 unnormalized pool steps on radius-10 boxes --------------------
    float* bin = buf0;
    float* bout = buf1;
    for (int k = 0; k < NIT; ++k) {
        float m0 = 0.f, m1 = 0.f;
        for (int i = tid; i < 64 * BOX3; i += nthreads) {
            int box = i / BOX3, r = i - box * BOX3;
            int dz = r / (BOX * BOX); r -= dz * (BOX * BOX);
            int dy = r / BOX, dx = r - dy * BOX;
            int b = box >> 5;
            const int* e = ea + box * 3;
            int d = e[0] + dz - RAD, h = e[1] + dy - RAD, w = e[2] + dx - RAD;
            if (d < 0 || d >= DV || h < 0 || h >= HV || w < 0 || w >= WV) continue;
            const float* base = bin + (size_t)b * DHW;
            float s = 0.f;
            #pragma unroll
            for (int zz = -1; zz <= 1; ++zz) {
                int dd = d + zz;
                if (dd < 0 || dd >= DV) continue;
                #pragma unroll
                for (int yy = -1; yy <= 1; ++yy) {
                    int hh = h + yy;
                    if (hh < 0 || hh >= HV) continue;
                    #pragma unroll
                    for (int xx = -1; xx <= 1; ++xx) {
                        int ww = w + xx;
                        if (ww < 0 || ww >= WV) continue;
                        s += base[(size_t)dd * HWV + (size_t)hh * WV + ww];
                    }
                }
            }
            size_t off = (size_t)d * HWV + (size_t)h * WV + w;
            size_t idx = (size_t)b * DHW + off;
            float val = s * (1.f / 27.f) * prob[idx];
            bout[idx] = val;                      // overlapping boxes: identical value
            if (b == 0) m0 = fmaxf(m0, val); else m1 = fmaxf(m1, val);
        }
        // Block-level max reduce (values >= 0), then plain per-block stores.
        #pragma unroll
        for (int o = 32; o > 0; o >>= 1) {
            m0 = fmaxf(m0, __shfl_down(m0, o));
            m1 = fmaxf(m1, __shfl_down(m1, o));
        }
        int wave = threadIdx.x >> 6;
        if ((threadIdx.x & 63) == 0) { sred[0][wave] = m0; sred[1][wave] = m1; }
        __syncthreads();
        if (threadIdx.x == 0) {
            gpart[(k * 2 + 0) * NBLK + blockIdx.x] =
                fmaxf(fmaxf(sred[0][0], sred[0][1]), fmaxf(sred[0][2], sred[0][3]));
            gpart[(k * 2 + 1) * NBLK + blockIdx.x] =
                fmaxf(fmaxf(sred[1][0], sred[1][1]), fmaxf(sred[1][2], sred[1][3]));
        }
        float* t = bin; bin = bout; bout = t;
        __threadfence();
        grid.sync();
    }

    // ---- Gather (block 0 only) -------------------------------------------
    if (blockIdx.x != 0) return;
    __shared__ float gm[NIT * BZ];
    __shared__ double sS[BZ];
    const int t = threadIdx.x;
    for (int c = 0; c < NIT * BZ; ++c) {
        float v = fmaxf(gpart[c * NBLK + t], gpart[c * NBLK + t + NTHR]);
        #pragma unroll
        for (int o = 32; o > 0; o >>= 1) v = fmaxf(v, __shfl_down(v, o));
        if ((t & 63) == 0) sred[0][t >> 6] = v;
        __syncthreads();
        if (t == 0)
            gm[c] = fmaxf(fmaxf(sred[0][0], sred[0][1]), fmaxf(sred[0][2], sred[0][3]));
        __syncthreads();
    }
    if (t < BZ) {
        double s = 1.0;
        for (int k = 0; k < NIT; ++k) {
            double den = s * (double)gm[k * 2 + t];
            if (den > 0.0) s = s / (den + SMOOTH);
        }
        sS[t] = s;
    }
    __syncthreads();
    float score = 0.f;
    if (t < BZ * NP) {
        int b = t / NP;
        const int* e = eb + t * 3;
        int d = e[0], h = e[1], w = e[2];
        bool inr = false;
        for (int q = 0; q < NP; ++q) {
            const int* a = ea + (b * NP + q) * 3;
            if (abs(d - a[0]) <= RAD && abs(h - a[1]) <= RAD && abs(w - a[2]) <= RAD) {
                inr = true;
                break;
            }
        }
        // eb farther than RAD from every seed has heat exactly 0 (and its
        // ws voxel was never initialized -> must not be read).
        float val = inr ? bin[(size_t)b * DHW + (size_t)d * HWV + (size_t)h * WV + w]
                        : 0.f;
        score = (float)(sS[b] * (double)val);
    }
    #pragma unroll
    for (int o = 32; o > 0; o >>= 1) score += __shfl_down(score, o);
    if ((t & 63) == 0) sred[0][t >> 6] = score;
    __syncthreads();
    if (t == 0)
        out[0] = 1.f - (sred[0][0] + sred[0][1] + sred[0][2] + sred[0][3])
                       / (float)(BZ * NP);
}

// ---------------------------------------------------------------------------
extern "C" void kernel_launch(void* const* d_in, const int* in_sizes, int n_in,
                              void* d_out, int out_size, void* d_ws, size_t ws_size,
                              hipStream_t stream) {
    const float* logits = (const float*)d_in[0];
    // d_in[1] = labels (unused on device; endpoints were derived host-side)
    const int* ea = (const int*)d_in[2];
    const int* eb = (const int*)d_in[3];
    float* out = (float*)d_out;

    float* buf0 = (float*)d_ws;                 // BZ*DHW floats (64 MiB)
    float* buf1 = buf0 + BZ * DHW;              // BZ*DHW floats (64 MiB)
    float* prob = buf1 + BZ * DHW;              // BZ*DHW floats (64 MiB)
    float* gpart = prob + BZ * DHW;             // NIT*BZ*NBLK floats (40 KiB)

    void* args[] = {&logits, &ea, &eb, &out, &buf0, &buf1, &prob, &gpart};
    hipLaunchCooperativeKernel((const void*)cape_all, dim3(NBLK), dim3(NTHR),
                               args, 0, stream);
}

// Round 3
// 260.753 us; speedup vs baseline: 7.0442x; 7.0442x over previous
//
#include <hip/hip_runtime.h>
#include <cstddef>

// (B, C, D, H, W) = (2, 2, 128, 256, 256)
#define BZ   2
#define DV   128
#define HV   256
#define WV   256
#define NP   32                 // pairs per batch
#define NBOX (BZ*NP)            // 64 seed boxes
#define NIT  10
#define RAD  10
#define BOX  21                 // 2*RAD+1
#define BOXP 24                 // padded w-stride (16B-aligned lines)
#define UBOXSZ (BOX*BOX*BOXP)   // 12096 floats per box
#define HWV  65536
#define DHW  ((size_t)DV*HWV)
#define SMOOTH 1e-5f

// ===========================================================================
// K1: one workgroup per seed box. Evolve u_k = avgpool3(u_{k-1})*prob for 10
// steps entirely in LDS (exact: support radius k <= 10, zero outside box).
// Separable 3x3x3 box filter, 3 in-place passes/step with register staging.
// Writes final u_10 box to global, plus per-box max of u_9 (eps-term) and a
// duplicate-seed flag (duplicate seeds contribute once: .set semantics).
__global__ void __launch_bounds__(512)
evolve_kernel(const float* __restrict__ logits,
              const int* __restrict__ ea,
              float* __restrict__ u,        // [NBOX][21][21][24]
              float* __restrict__ g9part,   // [NBOX]
              int* __restrict__ dupflag)    // [NBOX]
{
    __shared__ float A[UBOXSZ];
    __shared__ float sred[8];
    __shared__ int sflag;

    const int box = blockIdx.x;
    const int b = box >> 5;
    const int t = threadIdx.x;

    const int sd = ea[box*3+0], sh = ea[box*3+1], sw = ea[box*3+2];

    if (t == 0) {
        int dup = 0;
        for (int q = b*NP; q < box; ++q)
            if (ea[q*3] == sd && ea[q*3+1] == sh && ea[q*3+2] == sw) { dup = 1; break; }
        sflag = dup;
        dupflag[box] = dup;
        if (dup) g9part[box] = 0.f;   // never evolved; K3 reads it
    }
    __syncthreads();
    if (sflag) return;

    // Zero field (incl. pads), then seed center = 1.0
    for (int i = t; i < UBOXSZ; i += 512) A[i] = 0.f;
    __syncthreads();
    if (t == 0) A[(RAD*BOX + RAD)*BOXP + RAD] = 1.0f;

    // Per-thread prob column for pass-3 ownership: (h,w) fixed, d in [0,21)
    float p[BOX];
    const int hh = (t < 441) ? t / BOX : 0;
    const int ww = (t < 441) ? t % BOX : 0;
    #pragma unroll
    for (int d = 0; d < BOX; ++d) p[d] = 0.f;
    if (t < 441) {
        const int gh = sh - RAD + hh;
        const int gw = sw - RAD + ww;
        if (gh >= 0 && gh < HV && gw >= 0 && gw < WV) {
            const float* lg = logits + (size_t)b * 2 * DHW;
            #pragma unroll
            for (int d = 0; d < BOX; ++d) {
                int gd = sd - RAD + d;
                if (gd >= 0 && gd < DV) {
                    size_t off = (size_t)gd * HWV + (size_t)gh * WV + gw;
                    float l0 = lg[off], l1 = lg[off + DHW];
                    p[d] = 1.f / (1.f + __expf(l0 - l1));  // softmax(C=2)[1]
                }
            }
        }
    }
    __syncthreads();

    const int dA = t / BOX;   // pass1/pass2 line coords
    const int hA = t % BOX;

    for (int k = 0; k < NIT; ++k) {
        // ---- pass 1: w-sums, in place, thread owns (d,h) w-line ----------
        if (t < 441) {
            float* base = &A[(dA*BOX + hA)*BOXP];    // 96B-aligned
            float r[BOX];
            #pragma unroll
            for (int i = 0; i < 5; ++i) {
                float4 q = ((float4*)base)[i];
                r[4*i] = q.x; r[4*i+1] = q.y; r[4*i+2] = q.z; r[4*i+3] = q.w;
            }
            r[20] = base[20];
            float s[BOX];
            #pragma unroll
            for (int w = 0; w < BOX; ++w) {
                float a = (w > 0)  ? r[w-1] : 0.f;
                float c = (w < 20) ? r[w+1] : 0.f;
                s[w] = a + r[w] + c;
            }
            #pragma unroll
            for (int i = 0; i < 5; ++i)
                ((float4*)base)[i] = make_float4(s[4*i], s[4*i+1], s[4*i+2], s[4*i+3]);
            base[20] = s[20];
        }
        __syncthreads();
        // ---- pass 2: h-sums, in place, thread owns (d,w) h-line ----------
        if (t < 441) {
            const int d = dA, w = hA;
            float c[BOX];
            #pragma unroll
            for (int h = 0; h < BOX; ++h) c[h] = A[(d*BOX + h)*BOXP + w];
            #pragma unroll
            for (int h = 0; h < BOX; ++h) {
                float a = (h > 0)  ? c[h-1] : 0.f;
                float e = (h < 20) ? c[h+1] : 0.f;
                A[(d*BOX + h)*BOXP + w] = a + c[h] + e;
            }
        }
        __syncthreads();
        // ---- pass 3: d-sums * prob/27, in place, thread owns (h,w) d-line
        float mymax = 0.f;
        if (t < 441) {
            float c[BOX];
            #pragma unroll
            for (int d = 0; d < BOX; ++d) c[d] = A[(d*BOX + hh)*BOXP + ww];
            #pragma unroll
            for (int d = 0; d < BOX; ++d) {
                float a = (d > 0)  ? c[d-1] : 0.f;
                float e = (d < 20) ? c[d+1] : 0.f;
                float v = (a + c[d] + e) * p[d] * (1.f/27.f);
                A[(d*BOX + hh)*BOXP + ww] = v;
                if (k == NIT-2) mymax = fmaxf(mymax, v);
            }
        }
        if (k == NIT-2) {   // per-box max of u_9 (eps-term in the recurrence)
            #pragma unroll
            for (int o = 32; o > 0; o >>= 1)
                mymax = fmaxf(mymax, __shfl_down(mymax, o));
            if ((t & 63) == 0) sred[t >> 6] = mymax;
            __syncthreads();
            if (t == 0) {
                float m = sred[0];
                for (int i = 1; i < 8; ++i) m = fmaxf(m, sred[i]);
                g9part[box] = m;
            }
        }
        __syncthreads();
    }

    // Stream final box (incl. zero pads) to global, coalesced float4.
    float4* dst = (float4*)(u + (size_t)box * UBOXSZ);
    const float4* src = (const float4*)A;
    for (int i = t; i < UBOXSZ/4; i += 512) dst[i] = src[i];
}

// ===========================================================================
// K2: exact final max g_N of the SUMMED field (overlapping boxes add).
// One WG per box; per-box overlap candidate list; max-reduce to gNpart.
__global__ void __launch_bounds__(256)
maxsum_kernel(const int* __restrict__ ea,
              const float* __restrict__ u,
              const int* __restrict__ dupflag,
              float* __restrict__ gNpart)
{
    const int box = blockIdx.x;
    const int b = box >> 5;
    const int t = threadIdx.x;

    if (dupflag[box]) { if (t == 0) gNpart[box] = 0.f; return; }

    __shared__ int list[NP];
    __shared__ int lseed[NP][3];
    __shared__ int nlist, myseed[3];
    __shared__ float sred[4];
    if (t == 0) {
        int n = 0;
        int sd = ea[box*3], sh = ea[box*3+1], sw = ea[box*3+2];
        myseed[0] = sd; myseed[1] = sh; myseed[2] = sw;
        for (int q = b*NP; q < (b+1)*NP; ++q) {
            if (q == box || dupflag[q]) continue;
            int qd = ea[q*3], qh = ea[q*3+1], qw = ea[q*3+2];
            if (abs(qd - sd) <= 2*RAD && abs(qh - sh) <= 2*RAD && abs(qw - sw) <= 2*RAD) {
                list[n] = q;
                lseed[n][0] = qd; lseed[n][1] = qh; lseed[n][2] = qw;
                ++n;
            }
        }
        nlist = n;
    }
    __syncthreads();

    const int sd = myseed[0], sh = myseed[1], sw = myseed[2];
    const int nl = nlist;
    float m = 0.f;
    for (int i = t; i < BOX*BOX*BOX; i += 256) {
        int d = i / (BOX*BOX), r = i % (BOX*BOX);
        int h = r / BOX, w = r % BOX;
        float v = u[(size_t)box * UBOXSZ + (d*BOX + h)*BOXP + w];
        int gd = sd - RAD + d, gh = sh - RAD + h, gw = sw - RAD + w;
        for (int j = 0; j < nl; ++j) {
            int ld = gd - lseed[j][0] + RAD;
            int lh = gh - lseed[j][1] + RAD;
            int lw = gw - lseed[j][2] + RAD;
            if (ld >= 0 && ld < BOX && lh >= 0 && lh < BOX && lw >= 0 && lw < BOX)
                v += u[(size_t)list[j] * UBOXSZ + (ld*BOX + lh)*BOXP + lw];
        }
        m = fmaxf(m, v);
    }
    #pragma unroll
    for (int o = 32; o > 0; o >>= 1) m = fmaxf(m, __shfl_down(m, o));
    if ((t & 63) == 0) sred[t >> 6] = m;
    __syncthreads();
    if (t == 0)
        gNpart[box] = fmaxf(fmaxf(sred[0], sred[1]), fmaxf(sred[2], sred[3]));
}

// ===========================================================================
// K3: t_N = g_N + eps*g9 (higher eps powers negligible at 1e-10);
// score = sum-over-covering-boxes u_10[eb] / t_N;  out = 1 - mean(score).
__global__ void final_kernel(const int* __restrict__ ea,
                             const int* __restrict__ eb,
                             const float* __restrict__ u,
                             const int* __restrict__ dupflag,
                             const float* __restrict__ gNpart,
                             const float* __restrict__ g9part,
                             float* __restrict__ out)
{
    const int t = threadIdx.x;   // 64 threads = 1 wave: (b, pair)
    const int b = t >> 5;
    float gN = 0.f, g9 = 0.f;
    for (int q = b*NP; q < (b+1)*NP; ++q) {
        gN = fmaxf(gN, gNpart[q]);
        g9 = fmaxf(g9, g9part[q]);
    }
    const float tden = gN + SMOOTH * g9;

    const int d = eb[t*3], h = eb[t*3+1], w = eb[t*3+2];
    float v = 0.f;
    for (int q = b*NP; q < (b+1)*NP; ++q) {
        if (dupflag[q]) continue;
        int ld = d - ea[q*3]   + RAD;
        int lh = h - ea[q*3+1] + RAD;
        int lw = w - ea[q*3+2] + RAD;
        if (ld >= 0 && ld < BOX && lh >= 0 && lh < BOX && lw >= 0 && lw < BOX)
            v += u[(size_t)q * UBOXSZ + (ld*BOX + lh)*BOXP + lw];
    }
    float score = (tden > 0.f) ? v / tden : 0.f;  // gN==0 => field dead => ref scores 0
    #pragma unroll
    for (int o = 32; o > 0; o >>= 1) score += __shfl_down(score, o);
    if (t == 0) out[0] = 1.f - score / (float)(BZ * NP);
}

// ===========================================================================
extern "C" void kernel_launch(void* const* d_in, const int* in_sizes, int n_in,
                              void* d_out, int out_size, void* d_ws, size_t ws_size,
                              hipStream_t stream) {
    const float* logits = (const float*)d_in[0];
    // d_in[1] = labels (host-side only)
    const int* ea = (const int*)d_in[2];
    const int* eb = (const int*)d_in[3];
    float* out = (float*)d_out;

    float* u      = (float*)d_ws;                       // 64*12096 floats (~3 MB)
    float* g9part = u + (size_t)NBOX * UBOXSZ;          // 64 floats
    float* gNpart = g9part + NBOX;                      // 64 floats
    int*   dflag  = (int*)(gNpart + NBOX);              // 64 ints

    evolve_kernel<<<NBOX, 512, 0, stream>>>(logits, ea, u, g9part, dflag);
    maxsum_kernel<<<NBOX, 256, 0, stream>>>(ea, u, dflag, gNpart);
    final_kernel<<<1, 64, 0, stream>>>(ea, eb, u, dflag, gNpart, g9part, out);
}

// Round 4
// 253.701 us; speedup vs baseline: 7.2400x; 1.0278x over previous
//
#include <hip/hip_runtime.h>
#include <cstddef>

// (B, C, D, H, W) = (2, 2, 128, 256, 256)
#define BZ   2
#define DV   128
#define HV   256
#define WV   256
#define NP   32                 // pairs per batch
#define NBOX (BZ*NP)            // 64 seed boxes
#define NIT  10
#define RAD  10
#define BOX  21                 // 2*RAD+1
#define BOX2 (BOX*BOX)          // 441
#define BOX3 (BOX*BOX*BOX)      // 9261
#define HWV  65536
#define DHW  ((size_t)DV*HWV)
#define SMOOTH 1e-5f

// ===========================================================================
// K1: one workgroup per seed box. Evolve u_k = avgpool3(u_{k-1})*prob for 10
// steps entirely in LDS. Tight (d*441 + h*21 + w) layout: stride-21 lane
// access is conflict-free (gcd(21,32)=1). Separable 3x3x3 filter, in-place
// register-ring passes. Emits per-box max of u_9 (eps term) and own-box max
// of u_10 (exact g_N for boxes with no overlapping neighbor).
__global__ void __launch_bounds__(512)
evolve_kernel(const float* __restrict__ logits,
              const int* __restrict__ ea,
              float* __restrict__ u,        // [NBOX][BOX3] tight
              float* __restrict__ g9part,   // [NBOX]
              float* __restrict__ gNpart,   // [NBOX] own-box max (K2 may overwrite)
              int* __restrict__ dupflag)    // [NBOX]
{
    __shared__ float A[BOX3];
    __shared__ float sred9[8], sredN[8];
    __shared__ int sflag;

    const int box = blockIdx.x;
    const int b = box >> 5;
    const int t = threadIdx.x;

    const int sd = ea[box*3+0], sh = ea[box*3+1], sw = ea[box*3+2];

    if (t == 0) {
        int dup = 0;
        for (int q = b*NP; q < box; ++q)
            if (ea[q*3] == sd && ea[q*3+1] == sh && ea[q*3+2] == sw) { dup = 1; break; }
        sflag = dup;
        dupflag[box] = dup;
        if (dup) { g9part[box] = 0.f; gNpart[box] = 0.f; }
    }
    __syncthreads();
    if (sflag) return;

    // Zero field, then seed center = 1.0
    for (int i = t; i < BOX3; i += 512) A[i] = 0.f;
    __syncthreads();
    if (t == 0) A[RAD*BOX2 + RAD*BOX + RAD] = 1.0f;

    // Per-thread prob column for pass-3 ownership: (h,w) = (t/21, t%21)
    float p[BOX];
    #pragma unroll
    for (int d = 0; d < BOX; ++d) p[d] = 0.f;
    if (t < BOX2) {
        const int hh = t / BOX, ww = t % BOX;
        const int gh = sh - RAD + hh;
        const int gw = sw - RAD + ww;
        if (gh >= 0 && gh < HV && gw >= 0 && gw < WV) {
            const float* lg = logits + (size_t)b * 2 * DHW;
            #pragma unroll
            for (int d = 0; d < BOX; ++d) {
                int gd = sd - RAD + d;
                if (gd >= 0 && gd < DV) {
                    size_t off = (size_t)gd * HWV + (size_t)gh * WV + gw;
                    float l0 = lg[off], l1 = lg[off + DHW];
                    p[d] = (1.f/27.f) / (1.f + __expf(l0 - l1)); // sigmoid/27
                }
            }
        }
    }
    __syncthreads();

    float max9 = 0.f, maxN = 0.f;

    for (int k = 0; k < NIT; ++k) {
        // ---- pass 1: w-sums in place; thread owns (d,h) line, base = 21*t.
        // Lane stride 21 dwords -> conflict-free.
        if (t < BOX2) {
            const int base = t * BOX;
            float prev = 0.f, cur = A[base], nxt;
            #pragma unroll
            for (int w = 0; w < BOX; ++w) {
                nxt = (w < BOX-1) ? A[base + w + 1] : 0.f;
                A[base + w] = prev + cur + nxt;
                prev = cur; cur = nxt;
            }
        }
        __syncthreads();
        // ---- pass 2: h-sums in place; thread owns (d,w): addr = d*441+h*21+w
        if (t < BOX2) {
            const int d = t / BOX, w = t % BOX;
            const int base = d * BOX2 + w;
            float prev = 0.f, cur = A[base], nxt;
            #pragma unroll
            for (int h = 0; h < BOX; ++h) {
                nxt = (h < BOX-1) ? A[base + (h+1)*BOX] : 0.f;
                A[base + h*BOX] = prev + cur + nxt;
                prev = cur; cur = nxt;
            }
        }
        __syncthreads();
        // ---- pass 3: d-sums * prob/27 in place; thread owns (h,w):
        // addr = d*441 + t -> lane-consecutive, conflict-free.
        if (t < BOX2) {
            float prev = 0.f, cur = A[t], nxt;
            #pragma unroll
            for (int d = 0; d < BOX; ++d) {
                nxt = (d < BOX-1) ? A[(d+1)*BOX2 + t] : 0.f;
                float v = (prev + cur + nxt) * p[d];
                A[d*BOX2 + t] = v;
                prev = cur; cur = nxt;
                if (k == NIT-2) max9 = fmaxf(max9, v);
                if (k == NIT-1) maxN = fmaxf(maxN, v);
            }
        }
        __syncthreads();
    }

    // Reduce per-box maxes (u_9 for the eps term, u_10 own-box max).
    #pragma unroll
    for (int o = 32; o > 0; o >>= 1) {
        max9 = fmaxf(max9, __shfl_down(max9, o));
        maxN = fmaxf(maxN, __shfl_down(maxN, o));
    }
    if ((t & 63) == 0) { sred9[t >> 6] = max9; sredN[t >> 6] = maxN; }
    __syncthreads();
    if (t == 0) {
        float m9 = sred9[0], mN = sredN[0];
        #pragma unroll
        for (int i = 1; i < 8; ++i) { m9 = fmaxf(m9, sred9[i]); mN = fmaxf(mN, sredN[i]); }
        g9part[box] = m9;
        gNpart[box] = mN;   // exact if no neighbor overlaps; else K2 overwrites
    }

    // Stream final box to global (lane-consecutive, coalesced).
    for (int i = t; i < BOX3; i += 512) u[(size_t)box * BOX3 + i] = A[i];
}

// ===========================================================================
// K2: for boxes whose field overlaps another box's field, recompute the max
// of the SUMMED field over this box's region (overlaps add). Early-exits
// (keeping evolve's own-box max) when there are no overlap neighbors.
__global__ void __launch_bounds__(256)
maxsum_kernel(const int* __restrict__ ea,
              const float* __restrict__ u,
              const int* __restrict__ dupflag,
              float* __restrict__ gNpart)
{
    const int box = blockIdx.x;
    const int b = box >> 5;
    const int t = threadIdx.x;

    __shared__ int list[NP];
    __shared__ int lseed[NP][3];
    __shared__ int nlist, myseed[3];
    __shared__ float sred[4];

    if (t == 0) {
        int n = 0;
        int sd = ea[box*3], sh = ea[box*3+1], sw = ea[box*3+2];
        myseed[0] = sd; myseed[1] = sh; myseed[2] = sw;
        if (!dupflag[box]) {
            for (int q = b*NP; q < (b+1)*NP; ++q) {
                if (q == box || dupflag[q]) continue;
                int qd = ea[q*3], qh = ea[q*3+1], qw = ea[q*3+2];
                if (abs(qd - sd) <= 2*RAD && abs(qh - sh) <= 2*RAD &&
                    abs(qw - sw) <= 2*RAD) {
                    list[n] = q;
                    lseed[n][0] = qd; lseed[n][1] = qh; lseed[n][2] = qw;
                    ++n;
                }
            }
        }
        nlist = n;
    }
    __syncthreads();

    const int nl = nlist;
    if (nl == 0) return;                      // evolve's own-box max is exact

    const int sd = myseed[0], sh = myseed[1], sw = myseed[2];
    float m = 0.f;
    for (int i = t; i < BOX3; i += 256) {
        int d = i / BOX2, r = i % BOX2;
        int h = r / BOX, w = r % BOX;
        float v = u[(size_t)box * BOX3 + i];
        int gd = sd - RAD + d, gh = sh - RAD + h, gw = sw - RAD + w;
        for (int j = 0; j < nl; ++j) {
            int ld = gd - lseed[j][0] + RAD;
            int lh = gh - lseed[j][1] + RAD;
            int lw = gw - lseed[j][2] + RAD;
            if (ld >= 0 && ld < BOX && lh >= 0 && lh < BOX && lw >= 0 && lw < BOX)
                v += u[(size_t)list[j] * BOX3 + (ld*BOX + lh)*BOX + lw];
        }
        m = fmaxf(m, v);
    }
    #pragma unroll
    for (int o = 32; o > 0; o >>= 1) m = fmaxf(m, __shfl_down(m, o));
    if ((t & 63) == 0) sred[t >> 6] = m;
    __syncthreads();
    if (t == 0)
        gNpart[box] = fmaxf(fmaxf(sred[0], sred[1]), fmaxf(sred[2], sred[3]));
}

// ===========================================================================
// K3: t_N = g_N + eps*g9 (higher eps powers < 1e-10 relative);
// score = sum-over-covering-boxes u_10[eb] / t_N;  out = 1 - mean(score).
__global__ void final_kernel(const int* __restrict__ ea,
                             const int* __restrict__ eb,
                             const float* __restrict__ u,
                             const int* __restrict__ dupflag,
                             const float* __restrict__ gNpart,
                             const float* __restrict__ g9part,
                             float* __restrict__ out)
{
    const int t = threadIdx.x;   // 64 threads = 1 wave: (b, pair)
    const int b = t >> 5;
    float gN = 0.f, g9 = 0.f;
    for (int q = b*NP; q < (b+1)*NP; ++q) {
        gN = fmaxf(gN, gNpart[q]);
        g9 = fmaxf(g9, g9part[q]);
    }
    const float tden = gN + SMOOTH * g9;

    const int d = eb[t*3], h = eb[t*3+1], w = eb[t*3+2];
    float v = 0.f;
    for (int q = b*NP; q < (b+1)*NP; ++q) {
        if (dupflag[q]) continue;
        int ld = d - ea[q*3]   + RAD;
        int lh = h - ea[q*3+1] + RAD;
        int lw = w - ea[q*3+2] + RAD;
        if (ld >= 0 && ld < BOX && lh >= 0 && lh < BOX && lw >= 0 && lw < BOX)
            v += u[(size_t)q * BOX3 + (ld*BOX + lh)*BOX + lw];
    }
    float score = (tden > 0.f) ? v / tden : 0.f;  // gN==0 => field dead => scores 0
    #pragma unroll
    for (int o = 32; o > 0; o >>= 1) score += __shfl_down(score, o);
    if (t == 0) out[0] = 1.f - score / (float)(BZ * NP);
}

// ===========================================================================
extern "C" void kernel_launch(void* const* d_in, const int* in_sizes, int n_in,
                              void* d_out, int out_size, void* d_ws, size_t ws_size,
                              hipStream_t stream) {
    const float* logits = (const float*)d_in[0];
    // d_in[1] = labels (host-side only)
    const int* ea = (const int*)d_in[2];
    const int* eb = (const int*)d_in[3];
    float* out = (float*)d_out;

    float* u      = (float*)d_ws;                       // 64*9261 floats (~2.3 MB)
    float* g9part = u + (size_t)NBOX * BOX3;            // 64 floats
    float* gNpart = g9part + NBOX;                      // 64 floats
    int*   dflag  = (int*)(gNpart + NBOX);              // 64 ints

    evolve_kernel<<<NBOX, 512, 0, stream>>>(logits, ea, u, g9part, gNpart, dflag);
    maxsum_kernel<<<NBOX, 256, 0, stream>>>(ea, u, dflag, gNpart);
    final_kernel<<<1, 64, 0, stream>>>(ea, eb, u, dflag, gNpart, g9part, out);
}